// Round 10
// baseline (150.667 us; speedup 1.0000x reference)
//
#include <hip/hip_runtime.h>
#include <hip/hip_bf16.h>
#include <stdint.h>

// Problem constants
#define BDIM 4096
#define CDIM 10000
#define DDIM 512
#define CPAD 10112  // 79 * 128, padded N so GEMM loads need no guards
#define GRID 1024   // 4 blocks/CU x 256 CUs, all resident
#define CHUNK 632   // tiles per XCD chunk (5056 / 8)
#define STRIDE_TILE (2 * 128 * DDIM)  // B elem advance per step (bn += 2)

typedef __bf16 bf16_t;
typedef __attribute__((ext_vector_type(2))) __bf16 bf16x2;
typedef __attribute__((ext_vector_type(8))) __bf16 bf16x8;
typedef __attribute__((ext_vector_type(2))) float f32x2;
typedef __attribute__((ext_vector_type(4))) float f32x4;

__device__ __forceinline__ void gl_lds16(const void* g, void* s) {
  __builtin_amdgcn_global_load_lds(
      (const __attribute__((address_space(1))) void*)g,
      (__attribute__((address_space(3))) void*)s, 16, 0, 0);
}

// --- fused prep: rows [0,BDIM) = feat, rows [BDIM,BDIM+CPAD) = weights ---
__global__ __launch_bounds__(256) void prep(
    const float* __restrict__ feat, const float* __restrict__ w,
    bf16_t* __restrict__ fb, bf16_t* __restrict__ wb,
    float* __restrict__ f2, float* __restrict__ w2,
    float* __restrict__ wout) {
  const int b = blockIdx.x;
  const int t = threadIdx.x;
  __shared__ float red[4];
  if (b < BDIM) {
    const f32x2 v = ((const f32x2*)(feat + (size_t)b * DDIM))[t];
    bf16x2 o;
    o.x = (__bf16)v.x;
    o.y = (__bf16)v.y;
    ((bf16x2*)fb)[(size_t)b * (DDIM / 2) + t] = o;
    float ss = v.x * v.x + v.y * v.y;
#pragma unroll
    for (int off = 32; off > 0; off >>= 1) ss += __shfl_down(ss, off);
    if ((t & 63) == 0) red[t >> 6] = ss;
    __syncthreads();
    if (t == 0) f2[b] = red[0] + red[1] + red[2] + red[3];
  } else {
    const int row = b - BDIM;
    if (row < CDIM) {
      const f32x2 v = ((const f32x2*)(w + (size_t)row * DDIM))[t];
      __builtin_nontemporal_store(v, (f32x2*)(wout + (size_t)row * DDIM) + t);
      bf16x2 o;
      o.x = (__bf16)v.x;
      o.y = (__bf16)v.y;
      ((bf16x2*)wb)[(size_t)row * (DDIM / 2) + t] = o;
      float ss = v.x * v.x + v.y * v.y;
#pragma unroll
      for (int off = 32; off > 0; off >>= 1) ss += __shfl_down(ss, off);
      if ((t & 63) == 0) red[t >> 6] = ss;
      __syncthreads();
      if (t == 0) w2[row] = red[0] + red[1] + red[2] + red[3];
    } else {
      bf16x2 z;
      z.x = (__bf16)0.0f;
      z.y = (__bf16)0.0f;
      ((bf16x2*)wb)[(size_t)row * (DDIM / 2) + t] = z;
      if (t == 0) w2[row] = 0.0f;
    }
  }
}

// --- persistent GEMM, 64x128 tile, cross-tile store-pipelined epilogue ---
// 4 waves (2x2), wave tile 32x64, acc[2][4]+stash[2][4] = 64 VGPR.
// 3-buffer staging (36 KB) + swizzled sbuf (4 KB) = 40960 B -> 4 blocks/CU.
// Per K-iter: STAGE(kt+2) [3 loads], DRAIN slice kt-1 [1 NT store/thread],
// SLICEW slice kt (LDS), 6 ds_read + 8 MFMA, then vmcnt(5)+lgkmcnt(0)+
// s_barrier: tile-loads guaranteed landed, stores get 2 iters of slack.
__global__ __launch_bounds__(256, 4) void rbf_gemm(
    const bf16_t* __restrict__ A,   // [4096][512] bf16  (feat)
    const bf16_t* __restrict__ Bw,  // [10112][512] bf16 (weights, padded)
    const float* __restrict__ f2g, const float* __restrict__ w2g,
    float* __restrict__ out) {
  __shared__ __align__(16) bf16_t stg[3 * 6144];  // 36 KB: 3 x (A 4KB|B 8KB)
  __shared__ __align__(16) float sbuf[2][4][128];  // 4 KB slice reshuffle

  const int b = blockIdx.x;
  const int t = threadIdx.x;
  const int lane = t & 63;
  const int wv = t >> 6;
  const int wm2 = (wv >> 1) * 32;  // feat-row group of this wave
  const int wn2 = (wv & 1) * 64;   // weight-col group of this wave
  const int fr = lane & 15;
  const int k8 = (lane >> 4) * 8;
  const int c_l = (lane >> 4) * 4;

  // tile decode: wg = chunk-swizzled index; steps advance wg by 128 within
  // the same XCD chunk -> bm (wg&63) constant, bn (wg>>6) advances by 2.
  const int off = b >> 3;
  const int wg0 = (b & 7) * CHUNK + off;
  const int bm = wg0 & 63;   // 0..63 (M tiles of 64 rows)
  const int bn0 = wg0 >> 6;  // 0..78
  const int s_total = (CHUNK - 1 - off) / 128 + 1;  // 4 or 5

  // per-thread f2 rows (feat-row of each mi frag)
  float f2r[2];
#pragma unroll
  for (int mi = 0; mi < 2; ++mi)
    f2r[mi] = f2g[bm * 64 + wm2 + mi * 16 + fr];

  // staging addressing
  const int sr = t >> 2;        // 0..63
  const int sc = (t & 3) * 8;   // 0,8,16,24
  const bf16_t* gaA = A + (size_t)(bm * 64 + sr) * DDIM + sc;
  const bf16_t* gb_cur = Bw + (size_t)(bn0 * 128 + sr) * DDIM + sc;
  const bf16_t* gb_nxt = gb_cur + (s_total > 1 ? STRIDE_TILE : 0);

  // buffer layout (elems): A [0,2048), B [2048,6144); buffers 0/6144/12288
#define STAGE(o_, ak, bptr, bk)                                        \
  do {                                                                 \
    gl_lds16(gaA + (ak), stg + (o_) + t * 8);                          \
    gl_lds16((bptr) + (bk), stg + (o_) + 2048 + t * 8);                \
    gl_lds16((bptr) + (bk) + (size_t)64 * DDIM,                        \
             stg + (o_) + 4096 + t * 8);                               \
  } while (0)

  // write slice k (rows [4k,4k+4) of this block's 64) from stash -> sbuf
#define SLICEW(k)                                                      \
  do {                                                                 \
    if (((wv >> 1) == ((k) >> 3)) && ((fr >> 2) == ((k) & 3))) {       \
      const int row_ = fr & 3;                                         \
      const int mi_ = ((k) >> 2) & 1;                                  \
      _Pragma("unroll") for (int ni = 0; ni < 4; ++ni) {               \
        const int g_ = (wn2 >> 2) + ni * 4 + (lane >> 4);              \
        const int q_ = (g_ & ~7) | ((g_ + 4 * row_) & 7);              \
        *(f32x4*)&sbuf[(k) & 1][row_][q_ * 4] = stash[mi_][ni];        \
      }                                                                \
    }                                                                  \
  } while (0)

  // drain slice k to both output segments: 1 NT store per thread
#define DRAIN(k, bnd)                                                  \
  do {                                                                 \
    const int seg_ = t >> 7;                                           \
    const int u_ = t & 127;                                            \
    const int r_ = u_ >> 5;                                            \
    const int g_ = u_ & 31;                                            \
    const int q_ = (g_ & ~7) | ((g_ + 4 * r_) & 7);                    \
    const f32x4 v_ = *(const f32x4*)&sbuf[(k) & 1][r_][q_ * 4];        \
    const int gcol_ = (bnd)*128 + g_ * 4;                              \
    if (gcol_ < CDIM) {                                                \
      float* p_ = out + (size_t)(bm * 64 + (k)*4 + r_) * CDIM + gcol_; \
      if (seg_) p_ += BC;                                              \
      __builtin_nontemporal_store(v_, (f32x4*)p_);                     \
    }                                                                  \
  } while (0)

  const size_t BC = (size_t)BDIM * CDIM;

  f32x4 acc[2][4];
  f32x4 stash[2][4];
#pragma unroll
  for (int i = 0; i < 2; ++i)
#pragma unroll
    for (int j = 0; j < 4; ++j) acc[i][j] = (f32x4){0.f, 0.f, 0.f, 0.f};

  // prologue: k-tiles 0,1 of tile 0; full sync (covers f2r loads too)
  STAGE(0, 0, gb_cur, 0);
  STAGE(6144, 32, gb_cur, 32);
  __syncthreads();

  int o0 = 0, o1 = 6144, o2 = 12288;
  int bn_dr = bn0;  // bn of tile being drained (tile s-1)

  for (int s = 0; s < s_total; ++s) {
    const bool hasst = (s > 0);
    const int bn = bn0 + 2 * s;
#pragma unroll
    for (int kt = 0; kt < 16; ++kt) {
      // (1) stage k-tile kt+2 (last 2 iters: k0,k1 of next tile)
      if (kt <= 13)
        STAGE(o2, (kt + 2) * 32, gb_cur, (kt + 2) * 32);
      else
        STAGE(o2, ((kt + 2) & 15) * 32, gb_nxt, ((kt + 2) & 15) * 32);
      // (2) drain slice kt-1 of previous tile (after STAGE: stores newest)
      if (hasst && kt >= 1) DRAIN(kt - 1, bn_dr);
      // (3) reshuffle slice kt of previous tile's stash into sbuf
      if (hasst) SLICEW(kt);
      // (4) frags + MFMA from buffer o0
      {
        const bf16_t* Ab = stg + o0;
        bf16x8 af[2], wf[4];
#pragma unroll
        for (int mi = 0; mi < 2; ++mi)
          af[mi] = *(const bf16x8*)(Ab + (wm2 + mi * 16 + fr) * 32 + k8);
#pragma unroll
        for (int ni = 0; ni < 4; ++ni)
          wf[ni] = *(const bf16x8*)(Ab + 2048 + (wn2 + ni * 16 + fr) * 32 + k8);
        __builtin_amdgcn_s_setprio(1);
#pragma unroll
        for (int mi = 0; mi < 2; ++mi)
#pragma unroll
          for (int ni = 0; ni < 4; ++ni)
            acc[mi][ni] = __builtin_amdgcn_mfma_f32_16x16x32_bf16(
                wf[ni], af[mi], acc[mi][ni], 0, 0, 0);  // swapped: D = W F^T
        __builtin_amdgcn_s_setprio(0);
      }
      // (5) counted barrier: next buffer's 3 loads landed; stores keep
      // flying with ~2 iters of slack (see audit in header comment)
      if (hasst)
        asm volatile("s_waitcnt vmcnt(5) lgkmcnt(0)" ::: "memory");
      else
        asm volatile("s_waitcnt vmcnt(3) lgkmcnt(0)" ::: "memory");
      __builtin_amdgcn_s_barrier();
      const int tmp = o0;
      o0 = o1;
      o1 = o2;
      o2 = tmp;
    }
    // tile boundary: final slice of previous tile, then exp -> stash
    if (hasst) DRAIN(15, bn_dr);
    f32x4 w2v[4];
#pragma unroll
    for (int ni = 0; ni < 4; ++ni)
      w2v[ni] = *(const f32x4*)(w2g + bn * 128 + wn2 + ni * 16 + c_l);
#pragma unroll
    for (int mi = 0; mi < 2; ++mi) {
      const float fv = f2r[mi];
#pragma unroll
      for (int ni = 0; ni < 4; ++ni) {
        f32x4 st;
#pragma unroll
        for (int j = 0; j < 4; ++j) {
          float m = fv + w2v[ni][j] - 2.0f * acc[mi][ni][j];
          m = fmaxf(m, 0.0f);
          st[j] = __expf(-0.01f * m);
        }
        stash[mi][ni] = st;
        acc[mi][ni] = (f32x4){0.f, 0.f, 0.f, 0.f};
      }
    }
    bn_dr = bn;
    gb_cur = gb_nxt;
    if (s + 2 < s_total) gb_nxt += STRIDE_TILE;
  }

  // tail: drain the last tile's stash in 16 mini-phases
#pragma unroll
  for (int k = 0; k < 16; ++k) {
    SLICEW(k);
    asm volatile("s_waitcnt lgkmcnt(0)" ::: "memory");
    __builtin_amdgcn_s_barrier();
    DRAIN(k, bn_dr);
  }
#undef STAGE
#undef SLICEW
#undef DRAIN
}

extern "C" void kernel_launch(void* const* d_in, const int* in_sizes, int n_in,
                              void* d_out, int out_size, void* d_ws,
                              size_t ws_size, hipStream_t stream) {
  const float* feat = (const float*)d_in[0];
  // d_in[1] = label (int64) — unused by the reference math
  const float* w = (const float*)d_in[2];
  float* out = (float*)d_out;

  char* ws = (char*)d_ws;
  bf16_t* fb = (bf16_t*)ws;                        // 4096*512*2  = 4,194,304 B
  bf16_t* wb = (bf16_t*)(ws + 4194304);            // 10112*512*2 = 10,354,688 B
  float* f2 = (float*)(ws + 4194304 + 10354688);   // 16,384 B
  float* w2 = (float*)(ws + 4194304 + 10354688 + 16384);  // 40,448 B

  float* wout = out + (size_t)2 * BDIM * CDIM;  // weights passthrough segment

  prep<<<BDIM + CPAD, 256, 0, stream>>>(feat, w, fb, wb, f2, w2, wout);
  rbf_gemm<<<GRID, 256, 0, stream>>>(fb, wb, f2, w2, out);
}

// Round 11
// 110.398 us; speedup vs baseline: 1.3648x; 1.3648x over previous
//
#include <hip/hip_runtime.h>
#include <hip/hip_bf16.h>
#include <stdint.h>

// Problem constants
#define BDIM 4096
#define CDIM 10000
#define DDIM 512
#define CPAD 10112  // 79 * 128, padded N so GEMM loads need no guards
#define NT 16       // K tiles (512 / 32)

typedef __bf16 bf16_t;
typedef __attribute__((ext_vector_type(2))) __bf16 bf16x2;
typedef __attribute__((ext_vector_type(8))) __bf16 bf16x8;
typedef __attribute__((ext_vector_type(2))) float f32x2;
typedef __attribute__((ext_vector_type(4))) float f32x4;

__device__ __forceinline__ void gl_lds16(const void* g, void* s) {
  // async global->LDS, 16B per lane; LDS dest = wave-uniform base + lane*16
  __builtin_amdgcn_global_load_lds(
      (const __attribute__((address_space(1))) void*)g,
      (__attribute__((address_space(3))) void*)s, 16, 0, 0);
}

// LDS-only barrier: waits ds ops (lgkmcnt) but lets NT stores keep flying
// (plain __syncthreads emits s_waitcnt vmcnt(0) which drains stores).
__device__ __forceinline__ void lds_barrier() {
  asm volatile("s_waitcnt lgkmcnt(0)" ::: "memory");
  __builtin_amdgcn_s_barrier();
  __builtin_amdgcn_sched_barrier(0);
}

// --- fused prep: rows [0,BDIM) = feat, rows [BDIM,BDIM+CPAD) = weights ---
__global__ __launch_bounds__(256) void prep(
    const float* __restrict__ feat, const float* __restrict__ w,
    bf16_t* __restrict__ fb, bf16_t* __restrict__ wb,
    float* __restrict__ f2, float* __restrict__ w2,
    float* __restrict__ wout) {
  const int b = blockIdx.x;
  const int t = threadIdx.x;
  __shared__ float red[4];
  if (b < BDIM) {
    const f32x2 v = ((const f32x2*)(feat + (size_t)b * DDIM))[t];
    bf16x2 o;
    o.x = (__bf16)v.x;
    o.y = (__bf16)v.y;
    ((bf16x2*)fb)[(size_t)b * (DDIM / 2) + t] = o;
    float ss = v.x * v.x + v.y * v.y;
#pragma unroll
    for (int off = 32; off > 0; off >>= 1) ss += __shfl_down(ss, off);
    if ((t & 63) == 0) red[t >> 6] = ss;
    __syncthreads();
    if (t == 0) f2[b] = red[0] + red[1] + red[2] + red[3];
  } else {
    const int row = b - BDIM;
    if (row < CDIM) {
      const f32x2 v = ((const f32x2*)(w + (size_t)row * DDIM))[t];
      __builtin_nontemporal_store(v, (f32x2*)(wout + (size_t)row * DDIM) + t);
      bf16x2 o;
      o.x = (__bf16)v.x;
      o.y = (__bf16)v.y;
      ((bf16x2*)wb)[(size_t)row * (DDIM / 2) + t] = o;
      float ss = v.x * v.x + v.y * v.y;
#pragma unroll
      for (int off = 32; off > 0; off >>= 1) ss += __shfl_down(ss, off);
      if ((t & 63) == 0) red[t >> 6] = ss;
      __syncthreads();
      if (t == 0) w2[row] = red[0] + red[1] + red[2] + red[3];
    } else {
      bf16x2 z;
      z.x = (__bf16)0.0f;
      z.y = (__bf16)0.0f;
      ((bf16x2*)wb)[(size_t)row * (DDIM / 2) + t] = z;
      if (t == 0) w2[row] = 0.0f;
    }
  }
}

// --- main GEMM + RBF epilogue ---
// R8 structure (best: 109.8 µs): 128x128 tile, BK=32, 4 waves (2x2),
// mfma(wfrag, ffrag) operand-swapped, 2-buffer LDS (32 KB) 2-phase loop,
// 4 blocks/CU, LDS-staged coalesced NT epilogue with XOR bank-swizzle.
// R11 single variable: epilogue barriers are LDS-only (lgkmcnt) so the
// NT store bursts retire asynchronously instead of being drained by the
// vmcnt(0) inside __syncthreads (was ~2 x ~1000 cyc stall per block,
// convoying all 4 resident blocks).
__global__ __launch_bounds__(256, 4) void rbf_gemm(
    const bf16_t* __restrict__ A,   // [4096][512] bf16  (feat)
    const bf16_t* __restrict__ Bw,  // [10112][512] bf16 (weights, padded)
    const float* __restrict__ f2g, const float* __restrict__ w2g,
    float* __restrict__ out) {
  // pool: K-loop = 2 x [A(8KB) B(8KB)]; epilogue = resh 64x128 f32 (32KB)
  __shared__ __align__(16) char pool[32768];
  bf16_t* Pb = (bf16_t*)pool;  // buf b: A @ b*8192, B @ b*8192+4096 (elems)
  __shared__ float f2s[128];
  __shared__ float w2s[128];

  // 1-D grid, bijective XCD swizzle (nwg = 2528 = 8*316), bm fastest
  // (R5/R6 A/B: bm-fastest wins — concurrent blocks share the B-tile).
  const int bid = blockIdx.x;
  const int wg = (bid & 7) * (2528 / 8) + (bid >> 3);
  const int bm = wg & 31;  // 0..31 (M tiles) -- fastest within XCD chunk
  const int bn = wg >> 5;  // 0..78 (N tiles)
  const int t = threadIdx.x;
  const int lane = t & 63;

  if (t < 128)
    f2s[t] = f2g[bm * 128 + t];
  else
    w2s[t - 128] = w2g[bn * 128 + (t - 128)];

  // staging addressing: 4 threads x 16B per 32-elem row; 64 rows per call
  const int sr = t >> 2;
  const int sc = (t & 3) * 8;
  const bf16_t* ga0 = A + (size_t)(bm * 128 + sr) * DDIM + sc;
  const bf16_t* ga1 = ga0 + (size_t)64 * DDIM;
  const bf16_t* gb0 = Bw + (size_t)(bn * 128 + sr) * DDIM + sc;
  const bf16_t* gb1 = gb0 + (size_t)64 * DDIM;

  const int wv = t >> 6;
  const int wm = (wv >> 1) * 64;  // feat group of this wave
  const int wn = (wv & 1) * 64;   // weight group of this wave
  const int fr = lane & 15;
  const int k8 = (lane >> 4) * 8;

#define STAGE(b, kt)                                \
  do {                                              \
    const int k0_ = (kt) * 32;                      \
    bf16_t* Ab_ = Pb + (b) * 8192;                  \
    gl_lds16(ga0 + k0_, Ab_ + t * 8);               \
    gl_lds16(ga1 + k0_, Ab_ + 2048 + t * 8);        \
    gl_lds16(gb0 + k0_, Ab_ + 4096 + t * 8);        \
    gl_lds16(gb1 + k0_, Ab_ + 4096 + 2048 + t * 8); \
  } while (0)

  f32x4 acc[4][4];
#pragma unroll
  for (int i = 0; i < 4; ++i)
#pragma unroll
    for (int j = 0; j < 4; ++j) acc[i][j] = (f32x4){0.f, 0.f, 0.f, 0.f};

  STAGE(0, 0);
  __syncthreads();  // drains tile 0 + f2s/w2s

#pragma unroll
  for (int kt = 0; kt < NT; ++kt) {
    const int cur = kt & 1;
    if (kt + 1 < NT) STAGE(cur ^ 1, kt + 1);  // issue next-tile loads FIRST
    const bf16_t* Ab = Pb + cur * 8192;
    bf16x8 af[4], wf[4];
#pragma unroll
    for (int mi = 0; mi < 4; ++mi)
      af[mi] = *(const bf16x8*)(Ab + (wm + mi * 16 + fr) * 32 + k8);
#pragma unroll
    for (int ni = 0; ni < 4; ++ni)
      wf[ni] = *(const bf16x8*)(Ab + 4096 + (wn + ni * 16 + fr) * 32 + k8);
    __builtin_amdgcn_s_setprio(1);
#pragma unroll
    for (int mi = 0; mi < 4; ++mi)
#pragma unroll
      for (int ni = 0; ni < 4; ++ni)
        acc[mi][ni] = __builtin_amdgcn_mfma_f32_16x16x32_bf16(
            wf[ni], af[mi], acc[mi][ni], 0, 0, 0);  // swapped: D = W x F^T
    __builtin_amdgcn_s_setprio(0);
    if (kt + 1 < NT) __syncthreads();  // next buf landed; cur safe to reuse
  }

  __syncthreads();  // staging LDS now dead -> reuse as reshuffle tile
                    // (full sync: kt=15 ds_reads must land; no vmcnt pending)

  // Coalesced epilogue. resh = 64 rows x 128 floats, XOR bank-swizzle:
  // float4-group g at row r lives at g^... (bijective per row). Pass p
  // covers output rows [p*64, p*64+64), produced by waves with wm == p*64.
  float* resh = (float*)pool;
  const size_t BC = (size_t)BDIM * CDIM;
  const int m_l = lane & 15;
  const int c_l = (lane >> 4) * 4;

  for (int p = 0; p < 2; ++p) {
    if ((wv >> 1) == p) {
#pragma unroll
      for (int mi = 0; mi < 4; ++mi) {
        const int rl = mi * 16 + m_l;  // row within this 64-row half
        const float frow = f2s[wm + rl];
#pragma unroll
        for (int ni = 0; ni < 4; ++ni) {
          const int cl = wn + ni * 16 + c_l;
          f32x4 st;
#pragma unroll
          for (int j = 0; j < 4; ++j) {
            float m = frow + w2s[cl + j] - 2.0f * acc[mi][ni][j];
            m = fmaxf(m, 0.0f);
            st[j] = __expf(-0.01f * m);
          }
          *(f32x4*)(resh + rl * 128 + (((cl >> 2) ^ (rl & 31)) << 2)) = st;
        }
      }
    }
    lds_barrier();  // ds_writes visible; NT stores (if any) keep flying
    // stream 64 rows x 128 cols: 32 lanes x float4 = 512 B contiguous/row
    {
      const int rr = t >> 5;        // 0..7
      const int cc = (t & 31) * 4;  // 0..124
      const int gcol = bn * 128 + cc;
      if (gcol < CDIM) {
#pragma unroll
        for (int it = 0; it < 8; ++it) {
          const int r = it * 8 + rr;
          const f32x4 v =
              *(const f32x4*)(resh + r * 128 + (((cc >> 2) ^ (r & 31)) << 2));
          float* orow = out + (size_t)(bm * 128 + p * 64 + r) * CDIM + gcol;
          __builtin_nontemporal_store(v, (f32x4*)orow);
          __builtin_nontemporal_store(v, (f32x4*)(orow + BC));
        }
      }
    }
    lds_barrier();  // ds_reads in VGPRs -> resh reusable; stores async
  }
#undef STAGE
}

extern "C" void kernel_launch(void* const* d_in, const int* in_sizes, int n_in,
                              void* d_out, int out_size, void* d_ws,
                              size_t ws_size, hipStream_t stream) {
  const float* feat = (const float*)d_in[0];
  // d_in[1] = label (int64) — unused by the reference math
  const float* w = (const float*)d_in[2];
  float* out = (float*)d_out;

  char* ws = (char*)d_ws;
  bf16_t* fb = (bf16_t*)ws;                        // 4096*512*2  = 4,194,304 B
  bf16_t* wb = (bf16_t*)(ws + 4194304);            // 10112*512*2 = 10,354,688 B
  float* f2 = (float*)(ws + 4194304 + 10354688);   // 16,384 B
  float* w2 = (float*)(ws + 4194304 + 10354688 + 16384);  // 40,448 B

  float* wout = out + (size_t)2 * BDIM * CDIM;  // weights passthrough segment

  prep<<<BDIM + CPAD, 256, 0, stream>>>(feat, w, fb, wb, f2, w2, wout);
  rbf_gemm<<<2528, 256, 0, stream>>>(fb, wb, f2, w2, out);
}

// Round 12
// 106.767 us; speedup vs baseline: 1.4112x; 1.0340x over previous
//
#include <hip/hip_runtime.h>
#include <hip/hip_bf16.h>
#include <stdint.h>

// Problem constants
#define BDIM 4096
#define CDIM 10000
#define DDIM 512
#define CPAD 10112  // 79 * 128, padded N so GEMM loads need no guards
#define NT 16       // K tiles (512 / 32)

typedef __bf16 bf16_t;
typedef __attribute__((ext_vector_type(2))) __bf16 bf16x2;
typedef __attribute__((ext_vector_type(8))) __bf16 bf16x8;
typedef __attribute__((ext_vector_type(2))) float f32x2;
typedef __attribute__((ext_vector_type(4))) float f32x4;

__device__ __forceinline__ void gl_lds16(const void* g, void* s) {
  // async global->LDS, 16B per lane; LDS dest = wave-uniform base + lane*16
  __builtin_amdgcn_global_load_lds(
      (const __attribute__((address_space(1))) void*)g,
      (__attribute__((address_space(3))) void*)s, 16, 0, 0);
}

// LDS-only barrier: waits ds ops (lgkmcnt) but lets NT stores keep flying.
__device__ __forceinline__ void lds_barrier() {
  asm volatile("s_waitcnt lgkmcnt(0)" ::: "memory");
  __builtin_amdgcn_s_barrier();
  __builtin_amdgcn_sched_barrier(0);
}

// --- fused prep: rows [0,BDIM) = feat, rows [BDIM,BDIM+CPAD) = weights ---
__global__ __launch_bounds__(256) void prep(
    const float* __restrict__ feat, const float* __restrict__ w,
    bf16_t* __restrict__ fb, bf16_t* __restrict__ wb,
    float* __restrict__ f2, float* __restrict__ w2,
    float* __restrict__ wout) {
  const int b = blockIdx.x;
  const int t = threadIdx.x;
  __shared__ float red[4];
  if (b < BDIM) {
    const f32x2 v = ((const f32x2*)(feat + (size_t)b * DDIM))[t];
    bf16x2 o;
    o.x = (__bf16)v.x;
    o.y = (__bf16)v.y;
    ((bf16x2*)fb)[(size_t)b * (DDIM / 2) + t] = o;
    float ss = v.x * v.x + v.y * v.y;
#pragma unroll
    for (int off = 32; off > 0; off >>= 1) ss += __shfl_down(ss, off);
    if ((t & 63) == 0) red[t >> 6] = ss;
    __syncthreads();
    if (t == 0) f2[b] = red[0] + red[1] + red[2] + red[3];
  } else {
    const int row = b - BDIM;
    if (row < CDIM) {
      const f32x2 v = ((const f32x2*)(w + (size_t)row * DDIM))[t];
      __builtin_nontemporal_store(v, (f32x2*)(wout + (size_t)row * DDIM) + t);
      bf16x2 o;
      o.x = (__bf16)v.x;
      o.y = (__bf16)v.y;
      ((bf16x2*)wb)[(size_t)row * (DDIM / 2) + t] = o;
      float ss = v.x * v.x + v.y * v.y;
#pragma unroll
      for (int off = 32; off > 0; off >>= 1) ss += __shfl_down(ss, off);
      if ((t & 63) == 0) red[t >> 6] = ss;
      __syncthreads();
      if (t == 0) w2[row] = red[0] + red[1] + red[2] + red[3];
    } else {
      bf16x2 z;
      z.x = (__bf16)0.0f;
      z.y = (__bf16)0.0f;
      ((bf16x2*)wb)[(size_t)row * (DDIM / 2) + t] = z;
      if (t == 0) w2[row] = 0.0f;
    }
  }
}

// --- main GEMM + RBF epilogue ---
// R8/R11 K-loop (best): 128x128 tile, BK=32, 4 waves (2x2), operand-swapped
// mfma, 2-buffer LDS (32 KB) 2-phase loop, 4 blocks/CU.
// R12 single variable: BARRIER-FREE WAVE-PRIVATE EPILOGUE. Each wave owns an
// 8 KB slab (dead staging pool = 4 x 8 KB exactly) and streams its 64x64
// tile in 4 double-buffered 16-row chunks: exp -> swizzled ds_write ->
// ds_read -> dual NT store. No block barriers after the K-loop: waves drift
// apart, interleaving store bursts with other waves' VALU/LDS work; no
// thread idles (R11 idled half the block during each resh-fill pass).
__global__ __launch_bounds__(256, 4) void rbf_gemm(
    const bf16_t* __restrict__ A,   // [4096][512] bf16  (feat)
    const bf16_t* __restrict__ Bw,  // [10112][512] bf16 (weights, padded)
    const float* __restrict__ f2g, const float* __restrict__ w2g,
    float* __restrict__ out) {
  // pool: K-loop = 2 x [A(8KB) B(8KB)]; epilogue = 4 x 8KB wave slabs
  __shared__ __align__(16) char pool[32768];
  bf16_t* Pb = (bf16_t*)pool;  // buf b: A @ b*8192, B @ b*8192+4096 (elems)
  __shared__ float f2s[128];
  __shared__ float w2s[128];

  // 1-D grid, bijective XCD swizzle (nwg = 2528 = 8*316), bm fastest
  // (R5/R6 A/B: bm-fastest wins — concurrent blocks share the B-tile).
  const int bid = blockIdx.x;
  const int wg = (bid & 7) * (2528 / 8) + (bid >> 3);
  const int bm = wg & 31;  // 0..31 (M tiles) -- fastest within XCD chunk
  const int bn = wg >> 5;  // 0..78 (N tiles)
  const int t = threadIdx.x;
  const int lane = t & 63;

  if (t < 128)
    f2s[t] = f2g[bm * 128 + t];
  else
    w2s[t - 128] = w2g[bn * 128 + (t - 128)];

  // staging addressing: 4 threads x 16B per 32-elem row; 64 rows per call
  const int sr = t >> 2;
  const int sc = (t & 3) * 8;
  const bf16_t* ga0 = A + (size_t)(bm * 128 + sr) * DDIM + sc;
  const bf16_t* ga1 = ga0 + (size_t)64 * DDIM;
  const bf16_t* gb0 = Bw + (size_t)(bn * 128 + sr) * DDIM + sc;
  const bf16_t* gb1 = gb0 + (size_t)64 * DDIM;

  const int wv = t >> 6;
  const int wm = (wv >> 1) * 64;  // feat group of this wave
  const int wn = (wv & 1) * 64;   // weight group of this wave
  const int fr = lane & 15;
  const int k8 = (lane >> 4) * 8;
  const int g16 = lane >> 4;  // 0..3

#define STAGE(b, kt)                                \
  do {                                              \
    const int k0_ = (kt) * 32;                      \
    bf16_t* Ab_ = Pb + (b) * 8192;                  \
    gl_lds16(ga0 + k0_, Ab_ + t * 8);               \
    gl_lds16(ga1 + k0_, Ab_ + 2048 + t * 8);        \
    gl_lds16(gb0 + k0_, Ab_ + 4096 + t * 8);        \
    gl_lds16(gb1 + k0_, Ab_ + 4096 + 2048 + t * 8); \
  } while (0)

  f32x4 acc[4][4];
#pragma unroll
  for (int i = 0; i < 4; ++i)
#pragma unroll
    for (int j = 0; j < 4; ++j) acc[i][j] = (f32x4){0.f, 0.f, 0.f, 0.f};

  STAGE(0, 0);
  __syncthreads();  // drains tile 0 + f2s/w2s

#pragma unroll
  for (int kt = 0; kt < NT; ++kt) {
    const int cur = kt & 1;
    if (kt + 1 < NT) STAGE(cur ^ 1, kt + 1);  // issue next-tile loads FIRST
    const bf16_t* Ab = Pb + cur * 8192;
    bf16x8 af[4], wf[4];
#pragma unroll
    for (int mi = 0; mi < 4; ++mi)
      af[mi] = *(const bf16x8*)(Ab + (wm + mi * 16 + fr) * 32 + k8);
#pragma unroll
    for (int ni = 0; ni < 4; ++ni)
      wf[ni] = *(const bf16x8*)(Ab + 4096 + (wn + ni * 16 + fr) * 32 + k8);
    __builtin_amdgcn_s_setprio(1);
#pragma unroll
    for (int mi = 0; mi < 4; ++mi)
#pragma unroll
      for (int ni = 0; ni < 4; ++ni)
        acc[mi][ni] = __builtin_amdgcn_mfma_f32_16x16x32_bf16(
            wf[ni], af[mi], acc[mi][ni], 0, 0, 0);  // swapped: D = W x F^T
    __builtin_amdgcn_s_setprio(0);
    if (kt + 1 < NT) __syncthreads();  // next buf landed; cur safe to reuse
  }

  // all waves past their kt=15 ds_reads before slab reuse (no vmcnt pending:
  // kt=14's STAGE drained at its __syncthreads; kt=15 staged nothing)
  lds_barrier();

  // Barrier-free wave-private epilogue. Slab: 2 x [16][64] f32 (8 KB/wave).
  // Swizzle: col-group g (f32x4) at row r lives at q=(g+r)&15 -> 2-way max
  // on both ds_write and ds_read. Same-wave DS ops are in-order (WAR safe).
  float* slab = (float*)pool + wv * 2048;
  const size_t BC = (size_t)BDIM * CDIM;
  const int c_l = g16 * 4;

#pragma unroll
  for (int mi = 0; mi < 4; ++mi) {
    float* sb = slab + (mi & 1) * 1024;
    const float frow = f2s[wm + mi * 16 + fr];
    // fill: lane (fr, g16) covers row fr, col-groups g = ni*4+g16
#pragma unroll
    for (int ni = 0; ni < 4; ++ni) {
      const int cl = wn + ni * 16 + c_l;
      f32x4 st;
#pragma unroll
      for (int j = 0; j < 4; ++j) {
        float m = frow + w2s[cl + j] - 2.0f * acc[mi][ni][j];
        m = fmaxf(m, 0.0f);
        st[j] = __expf(-0.01f * m);
      }
      const int g = ni * 4 + g16;
      const int q = (g + fr) & 15;
      *(f32x4*)&sb[fr * 64 + q * 4] = st;
    }
    // drain: 4 rows/instr (r = s*4+g16), 16 lanes x 16 B = 256 B/row chunk
#pragma unroll
    for (int s = 0; s < 4; ++s) {
      const int r = s * 4 + g16;
      const int g2 = lane & 15;
      const int q2 = (g2 + r) & 15;
      const f32x4 v = *(const f32x4*)&sb[r * 64 + q2 * 4];
      const int gcol = bn * 128 + wn + g2 * 4;
      if (gcol < CDIM) {
        float* p = out + (size_t)(bm * 128 + wm + mi * 16 + r) * CDIM + gcol;
        __builtin_nontemporal_store(v, (f32x4*)p);
        __builtin_nontemporal_store(v, (f32x4*)(p + BC));
      }
    }
  }
#undef STAGE
}

extern "C" void kernel_launch(void* const* d_in, const int* in_sizes, int n_in,
                              void* d_out, int out_size, void* d_ws,
                              size_t ws_size, hipStream_t stream) {
  const float* feat = (const float*)d_in[0];
  // d_in[1] = label (int64) — unused by the reference math
  const float* w = (const float*)d_in[2];
  float* out = (float*)d_out;

  char* ws = (char*)d_ws;
  bf16_t* fb = (bf16_t*)ws;                        // 4096*512*2  = 4,194,304 B
  bf16_t* wb = (bf16_t*)(ws + 4194304);            // 10112*512*2 = 10,354,688 B
  float* f2 = (float*)(ws + 4194304 + 10354688);   // 16,384 B
  float* w2 = (float*)(ws + 4194304 + 10354688 + 16384);  // 40,448 B

  float* wout = out + (size_t)2 * BDIM * CDIM;  // weights passthrough segment

  prep<<<BDIM + CPAD, 256, 0, stream>>>(feat, w, fb, wb, f2, w2, wout);
  rbf_gemm<<<2528, 256, 0, stream>>>(fb, wb, f2, w2, out);
}